// Round 1
// baseline (404.302 us; speedup 1.0000x reference)
//
#include <hip/hip_runtime.h>
#include <hip/hip_bf16.h>

// Problem constants
#define B_     16
#define Q_     300
#define BQ     (B_*Q_)        // 4800
#define HIDDEN_ 256
#define NHEADS 8
#define DHEAD  32
#define PTOT   16             // points per head (4 levels x 4)
#define S_     13294
#define NOFF   256            // total_points*2
#define NATTN  128            // total_points
#define NCOLS  (NOFF+NATTN)   // 384 fused output columns
#define ROWS   16             // queries per projection block

// ---------------------------------------------------------------------------
// Kernel A: fused projection GEMM (h @ [W_off | W_attn]) + softmax + loc calc
// grid = 300 blocks, block = 384 threads (one output column per thread,
// 16 rows register-tiled). W is read once per block from L2.
// ---------------------------------------------------------------------------
__global__ __launch_bounds__(NCOLS) void proj_kernel(
    const float* __restrict__ hidden,   // (4800, 256)
    const float* __restrict__ refp,     // (4800, 4)
    const float* __restrict__ W_off,    // (256, 256)
    const float* __restrict__ b_off,    // (256)
    const float* __restrict__ W_attn,   // (256, 128)
    const float* __restrict__ b_attn,   // (128)
    float* __restrict__ aw_out,         // (4800, 128)  -> d_out segment 2
    float* __restrict__ loc_out)        // (4800, 8, 16, 2) -> workspace
{
    __shared__ float h_s[HIDDEN_ * ROWS];   // [k][r], 16 KB
    __shared__ float o_s[ROWS * NCOLS];     // [r][j], 24 KB

    const int row0 = blockIdx.x * ROWS;
    const int tid  = threadIdx.x;

    // Stage hidden tile, transposed to [k][r] so GEMM reads are float4-able
    for (int idx = tid; idx < HIDDEN_ * ROWS; idx += NCOLS) {
        int r = idx >> 8;          // idx / 256
        int k = idx & 255;         // idx % 256
        int row = row0 + r;
        h_s[k * ROWS + r] = (row < BQ) ? hidden[row * HIDDEN_ + k] : 0.f;
    }
    __syncthreads();

    // Column setup (wave-uniform branch: waves 0-3 -> W_off, waves 4-5 -> W_attn)
    const int j = tid;
    const float* Wcol;
    int stride;
    float bias;
    if (j < NOFF) { Wcol = W_off + j;         stride = NOFF;  bias = b_off[j]; }
    else          { Wcol = W_attn + (j-NOFF); stride = NATTN; bias = b_attn[j-NOFF]; }

    float acc[ROWS];
    #pragma unroll
    for (int r = 0; r < ROWS; ++r) acc[r] = bias;

    #pragma unroll 4
    for (int k = 0; k < HIDDEN_; ++k) {
        float w = Wcol[k * stride];
        const float4* hp = (const float4*)(&h_s[k * ROWS]);
        #pragma unroll
        for (int rv = 0; rv < ROWS / 4; ++rv) {
            float4 hv = hp[rv];                 // broadcast LDS read (conflict-free)
            acc[rv*4+0] = fmaf(hv.x, w, acc[rv*4+0]);
            acc[rv*4+1] = fmaf(hv.y, w, acc[rv*4+1]);
            acc[rv*4+2] = fmaf(hv.z, w, acc[rv*4+2]);
            acc[rv*4+3] = fmaf(hv.w, w, acc[rv*4+3]);
        }
    }

    #pragma unroll
    for (int r = 0; r < ROWS; ++r) o_s[r * NCOLS + j] = acc[r];
    __syncthreads();

    // Epilogue: 128 threads, one per (row, head): softmax + location compute
    if (tid < ROWS * NHEADS) {
        int r  = tid >> 3;
        int hd = tid & 7;
        int row = row0 + r;
        if (row < BQ) {
            float a[PTOT];
            float m = -1e30f;
            #pragma unroll
            for (int p = 0; p < PTOT; ++p) {
                a[p] = o_s[r * NCOLS + NOFF + hd * PTOT + p];
                m = fmaxf(m, a[p]);
            }
            float s = 0.f;
            #pragma unroll
            for (int p = 0; p < PTOT; ++p) { a[p] = __expf(a[p] - m); s += a[p]; }
            float inv = 1.f / s;

            float4 rp = ((const float4*)refp)[row];   // (cx, cy, w, h)
            const float sx = 0.25f * rp.z * 0.5f;     // scale(=1/4) * w * OFFSET_SCALE
            const float sy = 0.25f * rp.w * 0.5f;

            #pragma unroll
            for (int p = 0; p < PTOT; ++p) {
                float awv = a[p] * inv;
                aw_out[row * NATTN + hd * PTOT + p] = awv;
                float ox = o_s[r * NCOLS + (hd * PTOT + p) * 2];
                float oy = o_s[r * NCOLS + (hd * PTOT + p) * 2 + 1];
                float lx = rp.x + ox * sx;
                float ly = rp.y + oy * sy;
                ((float2*)loc_out)[(row * NHEADS + hd) * PTOT + p] = make_float2(lx, ly);
            }
        }
    }
}

// ---------------------------------------------------------------------------
// Kernel B: bilinear sampling + attention-weighted sum
// grid = 4800 blocks (one per (b,q)), block = 256 threads (8 heads x 32 chan)
// ---------------------------------------------------------------------------
__global__ __launch_bounds__(256) void sample_kernel(
    const float* __restrict__ enc,   // (16, 13294, 256)
    const float* __restrict__ aw,    // (4800, 128)
    const float* __restrict__ loc,   // (4800, 8, 16, 2)
    float* __restrict__ out)         // (4800, 256)
{
    const int bq  = blockIdx.x;
    const int b   = bq / Q_;
    const int tid = threadIdx.x;
    const int hd  = tid >> 5;
    const int c   = tid & 31;

    __shared__ float  aw_s[NHEADS * PTOT];       // 128
    __shared__ float2 loc_s[NHEADS * PTOT];      // 128 float2

    if (tid < NHEADS * PTOT) aw_s[tid] = aw[bq * NATTN + tid];
    ((float*)loc_s)[tid] = loc[bq * (NHEADS * PTOT * 2) + tid];
    __syncthreads();

    const float* encb = enc + (size_t)b * S_ * HIDDEN_;
    const int chan = hd * DHEAD + c;

    float acc = 0.f;
    #pragma unroll
    for (int p = 0; p < PTOT; ++p) {
        const int lvl = p >> 2;
        const int Wl    = (lvl == 0) ? 100 : (lvl == 1) ? 50 : (lvl == 2) ? 25 : 13;
        const int Hl    = Wl;
        const int start = (lvl == 0) ? 0 : (lvl == 1) ? 10000 : (lvl == 2) ? 12500 : 13125;

        float2 l = loc_s[hd * PTOT + p];
        float x = l.x * (float)Wl - 0.5f;
        float y = l.y * (float)Hl - 0.5f;
        float x0f = floorf(x), y0f = floorf(y);
        float wx1 = x - x0f, wx0 = 1.f - wx1;
        float wy1 = y - y0f, wy0 = 1.f - wy1;
        int x0 = (int)x0f, y0 = (int)y0f;
        int x1 = x0 + 1,  y1 = y0 + 1;

        // clipped indices (always in-bounds for the load; zero via valid mask)
        int x0c = x0 < 0 ? 0 : (x0 > Wl-1 ? Wl-1 : x0);
        int x1c = x1 < 0 ? 0 : (x1 > Wl-1 ? Wl-1 : x1);
        int y0c = y0 < 0 ? 0 : (y0 > Hl-1 ? Hl-1 : y0);
        int y1c = y1 < 0 ? 0 : (y1 > Hl-1 ? Hl-1 : y1);
        bool vx0 = (x0 >= 0) & (x0 <= Wl-1);
        bool vx1 = (x1 >= 0) & (x1 <= Wl-1);
        bool vy0 = (y0 >= 0) & (y0 <= Hl-1);
        bool vy1 = (y1 >= 0) & (y1 <= Hl-1);

        float v00 = encb[(size_t)(start + y0c * Wl + x0c) * HIDDEN_ + chan];
        float v01 = encb[(size_t)(start + y0c * Wl + x1c) * HIDDEN_ + chan];
        float v10 = encb[(size_t)(start + y1c * Wl + x0c) * HIDDEN_ + chan];
        float v11 = encb[(size_t)(start + y1c * Wl + x1c) * HIDDEN_ + chan];

        float s = 0.f;
        s += (vy0 & vx0) ? v00 * (wy0 * wx0) : 0.f;
        s += (vy0 & vx1) ? v01 * (wy0 * wx1) : 0.f;
        s += (vy1 & vx0) ? v10 * (wy1 * wx0) : 0.f;
        s += (vy1 & vx1) ? v11 * (wy1 * wx1) : 0.f;

        acc = fmaf(aw_s[hd * PTOT + p], s, acc);
    }

    out[bq * HIDDEN_ + tid] = acc;
}

extern "C" void kernel_launch(void* const* d_in, const int* in_sizes, int n_in,
                              void* d_out, int out_size, void* d_ws, size_t ws_size,
                              hipStream_t stream) {
    const float* hidden = (const float*)d_in[0];   // (16,300,256)
    const float* enc    = (const float*)d_in[1];   // (16,13294,256)
    const float* refp   = (const float*)d_in[2];   // (16,300,1,4)
    const float* W_off  = (const float*)d_in[3];   // (256,256)
    const float* b_off  = (const float*)d_in[4];   // (256)
    const float* W_attn = (const float*)d_in[5];   // (256,128)
    const float* b_attn = (const float*)d_in[6];   // (128)

    float* out    = (float*)d_out;                 // (4800,256)
    float* aw_out = out + (size_t)BQ * HIDDEN_;    // (4800,128)
    float* loc_ws = (float*)d_ws;                  // (4800,8,16,2) = 4.9 MB

    proj_kernel<<<BQ / ROWS, NCOLS, 0, stream>>>(
        hidden, refp, W_off, b_off, W_attn, b_attn, aw_out, loc_ws);
    sample_kernel<<<BQ, 256, 0, stream>>>(enc, aw_out, loc_ws, out);
}

// Round 2
// 310.351 us; speedup vs baseline: 1.3027x; 1.3027x over previous
//
#include <hip/hip_runtime.h>
#include <hip/hip_bf16.h>

// Problem constants
#define B_      16
#define Q_      300
#define BQ      (B_*Q_)        // 4800
#define HIDDEN_ 256
#define NHEADS  8
#define PTOT    16             // points per head (4 levels x 4)
#define S_      13294
#define NOFF    256            // total_points*2
#define NATTN   128            // total_points
#define NCOLS   (NOFF+NATTN)   // 384 fused output columns
#define OSTRIDE 388            // o_s row stride (row*388*4B -> 2-way bank alias = free)

typedef __attribute__((ext_vector_type(8))) short bf16x8;   // 8 bf16 (4 VGPRs)
typedef __attribute__((ext_vector_type(4))) float floatx4;  // MFMA C/D

// round-to-nearest-even f32 -> bf16 bits
__device__ __forceinline__ short f2bf(float f) {
    unsigned u = __float_as_uint(f);
    unsigned r = (u + 0x7fffu + ((u >> 16) & 1u)) >> 16;
    return (short)r;
}

// ---------------------------------------------------------------------------
// Kernel 0: build W^T in bf16:  Wt[j][k] = W[:,j][k]   (384 x 256, k-contig)
// ---------------------------------------------------------------------------
__global__ __launch_bounds__(256) void prep_kernel(
    const float* __restrict__ W_off,   // (256,256)
    const float* __restrict__ W_attn,  // (256,128)
    short* __restrict__ Wt)            // (384,256) bf16
{
    int id = blockIdx.x * 256 + threadIdx.x;   // 0 .. 98303
    int j = id >> 8;
    int k = id & 255;
    float v = (j < NOFF) ? W_off[k * NOFF + j] : W_attn[k * NATTN + (j - NOFF)];
    Wt[id] = f2bf(v);
}

// ---------------------------------------------------------------------------
// Kernel A: MFMA projection GEMM (16 rows x 384 cols x K=256 per block)
//           + bias + softmax + location epilogue.
// grid = 300, block = 256 (4 waves; each wave owns 6 16-col n-tiles)
// ---------------------------------------------------------------------------
__global__ __launch_bounds__(256) void proj_kernel(
    const float* __restrict__ hidden,   // (4800, 256) f32
    const float* __restrict__ refp,     // (4800, 4)
    const short* __restrict__ Wt,       // (384, 256) bf16, k-contiguous
    const float* __restrict__ b_off,    // (256)
    const float* __restrict__ b_attn,   // (128)
    float* __restrict__ aw_out,         // (4800, 128)
    float* __restrict__ loc_out)        // (4800, 8, 16, 2)
{
    __shared__ float o_s[16 * OSTRIDE];     // 24.8 KB logits

    const int tid  = threadIdx.x;
    const int wave = tid >> 6;
    const int lane = tid & 63;
    const int m    = lane & 15;             // row (A) / col (B/D)
    const int quad = lane >> 4;
    const int row0 = blockIdx.x * 16;

    floatx4 acc[6];
    #pragma unroll
    for (int i = 0; i < 6; ++i)
        #pragma unroll
        for (int r = 0; r < 4; ++r) acc[i][r] = 0.f;

    const float* hrow = hidden + (size_t)(row0 + m) * HIDDEN_;

    #pragma unroll
    for (int k0 = 0; k0 < HIDDEN_; k0 += 32) {
        const int kk = k0 + quad * 8;
        // A fragment: h[row0+m][kk .. kk+7], f32 -> bf16
        float4 a0 = *(const float4*)(hrow + kk);
        float4 a1 = *(const float4*)(hrow + kk + 4);
        bf16x8 af;
        af[0] = f2bf(a0.x); af[1] = f2bf(a0.y); af[2] = f2bf(a0.z); af[3] = f2bf(a0.w);
        af[4] = f2bf(a1.x); af[5] = f2bf(a1.y); af[6] = f2bf(a1.z); af[7] = f2bf(a1.w);
        #pragma unroll
        for (int i = 0; i < 6; ++i) {
            const int n0 = (wave * 6 + i) * 16;
            bf16x8 bf = *(const bf16x8*)(Wt + (size_t)(n0 + m) * HIDDEN_ + kk);
            acc[i] = __builtin_amdgcn_mfma_f32_16x16x32_bf16(af, bf, acc[i], 0, 0, 0);
        }
    }

    // D layout: col = lane&15, row = quad*4 + reg  (measured, m89/m91)
    #pragma unroll
    for (int i = 0; i < 6; ++i) {
        const int n0  = (wave * 6 + i) * 16;
        const int col = n0 + m;
        const float bias = (col < NOFF) ? b_off[col] : b_attn[col - NOFF];
        #pragma unroll
        for (int r = 0; r < 4; ++r) {
            const int row = quad * 4 + r;
            o_s[row * OSTRIDE + col] = acc[i][r] + bias;
        }
    }
    __syncthreads();

    // Epilogue: 128 threads, one per (row, head): softmax + location compute
    if (tid < 16 * NHEADS) {
        const int r  = tid >> 3;
        const int hd = tid & 7;
        const int row = row0 + r;

        float a[PTOT];
        float mx = -1e30f;
        #pragma unroll
        for (int p = 0; p < PTOT; ++p) {
            a[p] = o_s[r * OSTRIDE + NOFF + hd * PTOT + p];
            mx = fmaxf(mx, a[p]);
        }
        float s = 0.f;
        #pragma unroll
        for (int p = 0; p < PTOT; ++p) { a[p] = __expf(a[p] - mx); s += a[p]; }
        const float inv = 1.f / s;

        const float4 rp = ((const float4*)refp)[row];    // (cx, cy, w, h)
        const float sx = 0.25f * rp.z * 0.5f;            // scale(1/4) * w * OFFSET_SCALE
        const float sy = 0.25f * rp.w * 0.5f;

        #pragma unroll
        for (int p = 0; p < PTOT; ++p) {
            const float awv = a[p] * inv;
            aw_out[row * NATTN + hd * PTOT + p] = awv;
            const float ox = o_s[r * OSTRIDE + (hd * PTOT + p) * 2];
            const float oy = o_s[r * OSTRIDE + (hd * PTOT + p) * 2 + 1];
            ((float2*)loc_out)[(row * NHEADS + hd) * PTOT + p] =
                make_float2(rp.x + ox * sx, rp.y + oy * sy);
        }
    }
}

// ---------------------------------------------------------------------------
// Kernel B: bilinear sampling + weighted sum.
// block = 256 = 4 queries x 64 lanes; lane = head(8) x chan-quad(8).
// Each (head,point,tap) is exactly one 128-B line; dwordx4 gathers fetch
// 8 distinct full lines per wave-instruction (zero waste).
// ---------------------------------------------------------------------------
__global__ __launch_bounds__(256) void sample_kernel(
    const float* __restrict__ enc,   // (16, 13294, 256)
    const float* __restrict__ aw,    // (4800, 128)
    const float* __restrict__ loc,   // (4800, 8, 16, 2)
    float* __restrict__ out)         // (4800, 256)
{
    const int tid = threadIdx.x;
    const int g   = tid >> 6;            // query within block
    const int l   = tid & 63;
    const int bq  = blockIdx.x * 4 + g;
    const int b   = bq / Q_;
    const int hd  = l >> 3;
    const int cq  = l & 7;               // float4 index within head

    __shared__ float  aw_s[4][NATTN];
    __shared__ float2 loc_s[4][NATTN];

    for (int i = tid; i < 4 * NATTN; i += 256)
        aw_s[i >> 7][i & 127] = aw[(size_t)(blockIdx.x * 4 + (i >> 7)) * NATTN + (i & 127)];
    for (int i = tid; i < 4 * NATTN * 2; i += 256)
        ((float*)loc_s)[i] = loc[(size_t)blockIdx.x * 4 * (NATTN * 2) + i];
    __syncthreads();

    const float4* encb = (const float4*)(enc + (size_t)b * S_ * HIDDEN_);
    const int c4 = hd * 8 + cq;          // float4 column within a 64-float4 row

    float4 acc = make_float4(0.f, 0.f, 0.f, 0.f);

    #pragma unroll
    for (int p = 0; p < PTOT; ++p) {
        const int lvl   = p >> 2;
        const int Wl    = (lvl == 0) ? 100 : (lvl == 1) ? 50 : (lvl == 2) ? 25 : 13;
        const int start = (lvl == 0) ? 0 : (lvl == 1) ? 10000 : (lvl == 2) ? 12500 : 13125;

        const float2 lxy = loc_s[g][hd * PTOT + p];
        const float x = lxy.x * (float)Wl - 0.5f;
        const float y = lxy.y * (float)Wl - 0.5f;
        const float x0f = floorf(x), y0f = floorf(y);
        const float wx1 = x - x0f, wx0 = 1.f - wx1;
        const float wy1 = y - y0f, wy0 = 1.f - wy1;
        const int x0 = (int)x0f, y0 = (int)y0f;
        const int x1 = x0 + 1,  y1 = y0 + 1;

        const int x0c = x0 < 0 ? 0 : (x0 > Wl-1 ? Wl-1 : x0);
        const int x1c = x1 < 0 ? 0 : (x1 > Wl-1 ? Wl-1 : x1);
        const int y0c = y0 < 0 ? 0 : (y0 > Wl-1 ? Wl-1 : y0);
        const int y1c = y1 < 0 ? 0 : (y1 > Wl-1 ? Wl-1 : y1);
        const bool vx0 = (x0 >= 0) & (x0 <= Wl-1);
        const bool vx1 = (x1 >= 0) & (x1 <= Wl-1);
        const bool vy0 = (y0 >= 0) & (y0 <= Wl-1);
        const bool vy1 = (y1 >= 0) & (y1 <= Wl-1);

        const float w00 = (vy0 & vx0) ? wy0 * wx0 : 0.f;
        const float w01 = (vy0 & vx1) ? wy0 * wx1 : 0.f;
        const float w10 = (vy1 & vx0) ? wy1 * wx0 : 0.f;
        const float w11 = (vy1 & vx1) ? wy1 * wx1 : 0.f;

        const float4 v00 = encb[(size_t)(start + y0c * Wl + x0c) * 64 + c4];
        const float4 v01 = encb[(size_t)(start + y0c * Wl + x1c) * 64 + c4];
        const float4 v10 = encb[(size_t)(start + y1c * Wl + x0c) * 64 + c4];
        const float4 v11 = encb[(size_t)(start + y1c * Wl + x1c) * 64 + c4];

        float4 sm;
        sm.x = v00.x * w00 + v01.x * w01 + v10.x * w10 + v11.x * w11;
        sm.y = v00.y * w00 + v01.y * w01 + v10.y * w10 + v11.y * w11;
        sm.z = v00.z * w00 + v01.z * w01 + v10.z * w10 + v11.z * w11;
        sm.w = v00.w * w00 + v01.w * w01 + v10.w * w10 + v11.w * w11;

        const float a = aw_s[g][hd * PTOT + p];
        acc.x = fmaf(a, sm.x, acc.x);
        acc.y = fmaf(a, sm.y, acc.y);
        acc.z = fmaf(a, sm.z, acc.z);
        acc.w = fmaf(a, sm.w, acc.w);
    }

    *(float4*)(out + (size_t)bq * HIDDEN_ + l * 4) = acc;
}

extern "C" void kernel_launch(void* const* d_in, const int* in_sizes, int n_in,
                              void* d_out, int out_size, void* d_ws, size_t ws_size,
                              hipStream_t stream) {
    const float* hidden = (const float*)d_in[0];   // (16,300,256)
    const float* enc    = (const float*)d_in[1];   // (16,13294,256)
    const float* refp   = (const float*)d_in[2];   // (16,300,1,4)
    const float* W_off  = (const float*)d_in[3];   // (256,256)
    const float* b_off  = (const float*)d_in[4];   // (256)
    const float* W_attn = (const float*)d_in[5];   // (256,128)
    const float* b_attn = (const float*)d_in[6];   // (128)

    float* out    = (float*)d_out;                 // (4800,256)
    float* aw_out = out + (size_t)BQ * HIDDEN_;    // (4800,128)

    short* Wt     = (short*)d_ws;                  // 384x256 bf16 = 192 KB
    float* loc_ws = (float*)d_ws + 65536;          // (4800,8,16,2) @ +256 KB

    prep_kernel<<<NCOLS * HIDDEN_ / 256, 256, 0, stream>>>(W_off, W_attn, Wt);
    proj_kernel<<<BQ / 16, 256, 0, stream>>>(hidden, refp, Wt, b_off, b_attn, aw_out, loc_ws);
    sample_kernel<<<BQ / 4, 256, 0, stream>>>(enc, aw_out, loc_ws, out);
}

// Round 3
// 307.826 us; speedup vs baseline: 1.3134x; 1.0082x over previous
//
#include <hip/hip_runtime.h>
#include <hip/hip_bf16.h>

// Problem constants
#define B_      16
#define Q_      300
#define BQ      (B_*Q_)        // 4800
#define HIDDEN_ 256
#define NHEADS  8
#define PTOT    16             // points per head (4 levels x 4)
#define S_      13294
#define NOFF    256            // total_points*2
#define NATTN   128            // total_points
#define NCOLS   (NOFF+NATTN)   // 384 fused output columns
#define OSTRIDE 388            // o_s row stride
#define AS      264            // A_s row stride in bf16 (528 B -> 2-way bank alias = free)

typedef __attribute__((ext_vector_type(8))) short bf16x8;   // 8 bf16 (4 VGPRs)
typedef __attribute__((ext_vector_type(4))) float floatx4;  // MFMA C/D

// round-to-nearest-even f32 -> bf16 bits
__device__ __forceinline__ short f2bf(float f) {
    unsigned u = __float_as_uint(f);
    unsigned r = (u + 0x7fffu + ((u >> 16) & 1u)) >> 16;
    return (short)r;
}

// ---------------------------------------------------------------------------
// Kernel 0: build W^T in bf16:  Wt[j][k] = W[:,j][k]   (384 x 256, k-contig)
// ---------------------------------------------------------------------------
__global__ __launch_bounds__(256) void prep_kernel(
    const float* __restrict__ W_off,   // (256,256)
    const float* __restrict__ W_attn,  // (256,128)
    short* __restrict__ Wt)            // (384,256) bf16
{
    int id = blockIdx.x * 256 + threadIdx.x;   // 0 .. 98303
    int j = id >> 8;
    int k = id & 255;
    float v = (j < NOFF) ? W_off[k * NOFF + j] : W_attn[k * NATTN + (j - NOFF)];
    Wt[id] = f2bf(v);
}

// ---------------------------------------------------------------------------
// Kernel A: MFMA projection GEMM (16 rows x 384 cols x K=256 per block)
//           + bias + softmax + location epilogue.
// grid = 300, block = 512 (8 waves; each wave owns 3 16-col n-tiles).
// A staged once in LDS as bf16 (cooperative convert) -> no redundant
// per-wave global A loads / conversions.
// ---------------------------------------------------------------------------
__global__ __launch_bounds__(512) void proj_kernel(
    const float* __restrict__ hidden,   // (4800, 256) f32
    const float* __restrict__ refp,     // (4800, 4)
    const short* __restrict__ Wt,       // (384, 256) bf16, k-contiguous
    const float* __restrict__ b_off,    // (256)
    const float* __restrict__ b_attn,   // (128)
    float* __restrict__ aw_out,         // (4800, 128)
    float* __restrict__ loc_out)        // (4800, 8, 16, 2)
{
    __shared__ short A_s[16 * AS];          // 8.25 KB bf16 A tile
    __shared__ float o_s[16 * OSTRIDE];     // 24.8 KB logits

    const int tid  = threadIdx.x;
    const int wave = tid >> 6;              // 0..7
    const int lane = tid & 63;
    const int m    = lane & 15;             // row (A) / col (B/D)
    const int quad = lane >> 4;
    const int row0 = blockIdx.x * 16;

    // Stage A as bf16: thread t -> row r = t>>5, k-start = (t&31)*8
    {
        const int r  = tid >> 5;
        const int ks = (tid & 31) * 8;
        const float* hp = hidden + (size_t)(row0 + r) * HIDDEN_ + ks;
        float4 a0 = *(const float4*)hp;
        float4 a1 = *(const float4*)(hp + 4);
        bf16x8 v;
        v[0] = f2bf(a0.x); v[1] = f2bf(a0.y); v[2] = f2bf(a0.z); v[3] = f2bf(a0.w);
        v[4] = f2bf(a1.x); v[5] = f2bf(a1.y); v[6] = f2bf(a1.z); v[7] = f2bf(a1.w);
        *(bf16x8*)(A_s + r * AS + ks) = v;
    }
    __syncthreads();

    floatx4 acc[3];
    #pragma unroll
    for (int i = 0; i < 3; ++i)
        #pragma unroll
        for (int r = 0; r < 4; ++r) acc[i][r] = 0.f;

    #pragma unroll
    for (int k0 = 0; k0 < HIDDEN_; k0 += 32) {
        const int kk = k0 + quad * 8;
        bf16x8 af = *(const bf16x8*)(A_s + m * AS + kk);   // 2-way alias, free
        #pragma unroll
        for (int i = 0; i < 3; ++i) {
            const int n0 = (wave * 3 + i) * 16;
            bf16x8 bf = *(const bf16x8*)(Wt + (size_t)(n0 + m) * HIDDEN_ + kk);
            acc[i] = __builtin_amdgcn_mfma_f32_16x16x32_bf16(af, bf, acc[i], 0, 0, 0);
        }
    }

    // D layout: col = lane&15, row = quad*4 + reg  (measured, m89/m91)
    #pragma unroll
    for (int i = 0; i < 3; ++i) {
        const int n0  = (wave * 3 + i) * 16;
        const int col = n0 + m;
        const float bias = (col < NOFF) ? b_off[col] : b_attn[col - NOFF];
        #pragma unroll
        for (int r = 0; r < 4; ++r)
            o_s[(quad * 4 + r) * OSTRIDE + col] = acc[i][r] + bias;
    }
    __syncthreads();

    // Epilogue: 128 threads, one per (row, head): softmax + location compute
    if (tid < 16 * NHEADS) {
        const int r  = tid >> 3;
        const int hd = tid & 7;
        const int row = row0 + r;

        float a[PTOT];
        float mx = -1e30f;
        #pragma unroll
        for (int p = 0; p < PTOT; ++p) {
            a[p] = o_s[r * OSTRIDE + NOFF + hd * PTOT + p];
            mx = fmaxf(mx, a[p]);
        }
        float s = 0.f;
        #pragma unroll
        for (int p = 0; p < PTOT; ++p) { a[p] = __expf(a[p] - mx); s += a[p]; }
        const float inv = 1.f / s;

        const float4 rp = ((const float4*)refp)[row];    // (cx, cy, w, h)
        const float sx = 0.25f * rp.z * 0.5f;            // scale(1/4) * w * OFFSET_SCALE
        const float sy = 0.25f * rp.w * 0.5f;

        #pragma unroll
        for (int p = 0; p < PTOT; ++p) {
            const float awv = a[p] * inv;
            aw_out[row * NATTN + hd * PTOT + p] = awv;
            const float ox = o_s[r * OSTRIDE + (hd * PTOT + p) * 2];
            const float oy = o_s[r * OSTRIDE + (hd * PTOT + p) * 2 + 1];
            ((float2*)loc_out)[(row * NHEADS + hd) * PTOT + p] =
                make_float2(rp.x + ox * sx, rp.y + oy * sy);
        }
    }
}

// ---------------------------------------------------------------------------
// Kernel B: bilinear sampling + weighted sum.
// Phase 1: 512 (g,hd,p) tasks/block computed cooperatively -> LDS holds
//          per-tap {row-offset, weight*aw} (address math shared, not
//          redundantly done by all 8 lanes of a head).
// Phase 2: 64 taps x {ds_read_b64 (broadcast), dwordx4 gather, 4 FMA}.
// XCD-aware swizzle: batch b -> XCD b/2 (6.8 MB enc working set per XCD L2).
// ---------------------------------------------------------------------------
__global__ __launch_bounds__(256) void sample_kernel(
    const float* __restrict__ enc,   // (16, 13294, 256)
    const float* __restrict__ aw,    // (4800, 128)
    const float* __restrict__ loc,   // (4800, 8, 16, 2)
    float* __restrict__ out)         // (4800, 256)
{
    // blockIdx -> (batch, query-block) with XCD locality (bijective on 0..1199)
    const int xcd = blockIdx.x & 7;
    const int idx = blockIdx.x >> 3;             // 0..149
    const int hi  = (idx >= 75);
    const int bb  = xcd * 2 + hi;                // batch 0..15
    const int qb  = idx - hi * 75;               // 0..74
    const int bq0 = bb * Q_ + qb * 4;

    __shared__ float2 tw_s[4 * NHEADS * PTOT * 4];   // {.x=as_float(row), .y=w*aw}, 16 KB

    const int tid = threadIdx.x;

    // Phase 1: 512 point-tasks, 2 per thread
    for (int t = tid; t < 4 * NHEADS * PTOT; t += 256) {
        const int g    = t >> 7;          // query in block
        const int rest = t & 127;         // hd*16+p
        const int p    = rest & 15;
        const int bq   = bq0 + g;

        const float2 lxy = ((const float2*)loc)[(size_t)bq * NATTN + rest];
        const float  a   = aw[(size_t)bq * NATTN + rest];

        const int lvl   = p >> 2;
        const int Wl    = (lvl == 0) ? 100 : (lvl == 1) ? 50 : (lvl == 2) ? 25 : 13;
        const int start = (lvl == 0) ? 0 : (lvl == 1) ? 10000 : (lvl == 2) ? 12500 : 13125;

        const float x = lxy.x * (float)Wl - 0.5f;
        const float y = lxy.y * (float)Wl - 0.5f;
        const float x0f = floorf(x), y0f = floorf(y);
        const float wx1 = x - x0f, wx0 = 1.f - wx1;
        const float wy1 = y - y0f, wy0 = 1.f - wy1;
        const int x0 = (int)x0f, y0 = (int)y0f;
        const int x1 = x0 + 1,  y1 = y0 + 1;

        const int x0c = x0 < 0 ? 0 : (x0 > Wl-1 ? Wl-1 : x0);
        const int x1c = x1 < 0 ? 0 : (x1 > Wl-1 ? Wl-1 : x1);
        const int y0c = y0 < 0 ? 0 : (y0 > Wl-1 ? Wl-1 : y0);
        const int y1c = y1 < 0 ? 0 : (y1 > Wl-1 ? Wl-1 : y1);
        const bool vx0 = (x0 >= 0) & (x0 <= Wl-1);
        const bool vx1 = (x1 >= 0) & (x1 <= Wl-1);
        const bool vy0 = (y0 >= 0) & (y0 <= Wl-1);
        const bool vy1 = (y1 >= 0) & (y1 <= Wl-1);

        const int r00 = start + y0c * Wl + x0c;
        const int r01 = start + y0c * Wl + x1c;
        const int r10 = start + y1c * Wl + x0c;
        const int r11 = start + y1c * Wl + x1c;

        float2* dst = &tw_s[t * 4];
        dst[0] = make_float2(__int_as_float(r00), (vy0 & vx0) ? a * wy0 * wx0 : 0.f);
        dst[1] = make_float2(__int_as_float(r01), (vy0 & vx1) ? a * wy0 * wx1 : 0.f);
        dst[2] = make_float2(__int_as_float(r10), (vy1 & vx0) ? a * wy1 * wx0 : 0.f);
        dst[3] = make_float2(__int_as_float(r11), (vy1 & vx1) ? a * wy1 * wx1 : 0.f);
    }
    __syncthreads();

    // Phase 2: gather + accumulate
    const int g    = tid >> 6;           // query within block
    const int lane = tid & 63;
    const int hd   = lane >> 3;
    const int cq   = lane & 7;           // float4 index within head
    const int bq   = bq0 + g;

    const float4* encb = (const float4*)(enc + (size_t)bb * S_ * HIDDEN_);
    const int c4   = hd * 8 + cq;        // float4 column within 64-float4 row
    const int base = (g * NHEADS + hd) * PTOT * 4;

    float4 acc = make_float4(0.f, 0.f, 0.f, 0.f);

    #pragma unroll 16
    for (int i = 0; i < PTOT * 4; ++i) {
        const float2 tw = tw_s[base + i];         // broadcast across 8 lanes
        const int row = __float_as_int(tw.x);
        const float w = tw.y;
        const float4 v = encb[(size_t)row * 64 + c4];
        acc.x = fmaf(w, v.x, acc.x);
        acc.y = fmaf(w, v.y, acc.y);
        acc.z = fmaf(w, v.z, acc.z);
        acc.w = fmaf(w, v.w, acc.w);
    }

    ((float4*)out)[(size_t)bq * 64 + c4] = acc;
}

extern "C" void kernel_launch(void* const* d_in, const int* in_sizes, int n_in,
                              void* d_out, int out_size, void* d_ws, size_t ws_size,
                              hipStream_t stream) {
    const float* hidden = (const float*)d_in[0];   // (16,300,256)
    const float* enc    = (const float*)d_in[1];   // (16,13294,256)
    const float* refp   = (const float*)d_in[2];   // (16,300,1,4)
    const float* W_off  = (const float*)d_in[3];   // (256,256)
    const float* b_off  = (const float*)d_in[4];   // (256)
    const float* W_attn = (const float*)d_in[5];   // (256,128)
    const float* b_attn = (const float*)d_in[6];   // (128)

    float* out    = (float*)d_out;                 // (4800,256)
    float* aw_out = out + (size_t)BQ * HIDDEN_;    // (4800,128)

    short* Wt     = (short*)d_ws;                  // 384x256 bf16 = 192 KB
    float* loc_ws = (float*)d_ws + 65536;          // (4800,8,16,2) @ +256 KB

    prep_kernel<<<NCOLS * HIDDEN_ / 256, 256, 0, stream>>>(W_off, W_attn, Wt);
    proj_kernel<<<BQ / 16, 512, 0, stream>>>(hidden, refp, Wt, b_off, b_attn, aw_out, loc_ws);
    sample_kernel<<<BQ / 4, 256, 0, stream>>>(enc, aw_out, loc_ws, out);
}